// Round 1
// baseline (1419.122 us; speedup 1.0000x reference)
//
#include <hip/hip_runtime.h>
#include <math.h>

#define N_NODES 100000
#define N_EDGES 1600000
#define NF 16        // node features
#define HID 32
#define OUTD 12
#define CIN3 48      // x | T_o | T_i

// ---------------- zero workspace ----------------
__global__ void zero_kernel(float* __restrict__ p, int n) {
    int i = blockIdx.x * blockDim.x + threadIdx.x;
    int stride = gridDim.x * blockDim.x;
    for (; i < n; i += stride) p[i] = 0.0f;
}

// ---------------- weighted degrees ----------------
__global__ void degree_kernel(const int* __restrict__ ei, const float* __restrict__ ew,
                              float* __restrict__ deg_out, float* __restrict__ deg_in) {
    int e = blockIdx.x * blockDim.x + threadIdx.x;
    if (e >= N_EDGES) return;
    int src = ei[e];
    int dst = ei[N_EDGES + e];
    float w = ew[e];
    atomicAdd(&deg_out[src], w);
    atomicAdd(&deg_in[dst], w);
}

// ---------------- reciprocal in place ----------------
__global__ void rcp_kernel(float* __restrict__ deg_out, float* __restrict__ deg_in) {
    int n = blockIdx.x * blockDim.x + threadIdx.x;
    if (n >= N_NODES) return;
    deg_out[n] = 1.0f / deg_out[n];   // inf if degree 0 — never consumed (no such edge)
    deg_in[n]  = 1.0f / deg_in[n];
}

// ---------------- edge scatter: T_o / T_i ----------------
// thread t -> edge e = t>>4, feature f = t&15. 16 lanes per edge = coalesced 64B gathers.
__global__ __launch_bounds__(256)
void scatter_kernel(const int* __restrict__ ei, const float* __restrict__ x,
                    const float* __restrict__ inv_out, const float* __restrict__ inv_in,
                    float* __restrict__ To, float* __restrict__ Ti) {
    int t = blockIdx.x * blockDim.x + threadIdx.x;
    if (t >= N_EDGES * NF) return;
    int e = t >> 4;
    int f = t & 15;
    int src = ei[e];
    int dst = ei[N_EDGES + e];
    // forward diffusion: To[dst] += x[src] / deg_out[src]
    atomicAdd(&To[dst * NF + f], x[src * NF + f] * inv_out[src]);
    // reverse diffusion: Ti[src] += x[dst] / deg_in[dst]
    atomicAdd(&Ti[src * NF + f], x[dst * NF + f] * inv_in[dst]);
}

// ---------------- combine weights: Wc[c][h], c in [0,48) ----------------
// rows 0..15  : W[0,0,c,:] + W[1,0,c,:]   (K=0 term, both directions, only x-channels alive)
// rows 16..31 : W[0,1,c-16,:]             (forward diffusion)
// rows 32..47 : W[1,1,c-32,:]             (reverse diffusion)
// W layout [2,2,48,32]: (d,k,c,h) -> ((d*2+k)*48 + c)*32 + h
__global__ void wprep_kernel(const float* __restrict__ Wz, const float* __restrict__ Wh,
                             float* __restrict__ Wzc, float* __restrict__ Whc) {
    int t = blockIdx.x * blockDim.x + threadIdx.x;
    if (t >= 2 * CIN3 * HID) return;
    const float* W = (t < CIN3 * HID) ? Wz : Wh;
    float* Wc      = (t < CIN3 * HID) ? Wzc : Whc;
    int i = (t < CIN3 * HID) ? t : (t - CIN3 * HID);
    int c = i / HID;
    int h = i - c * HID;
    float v;
    if (c < 16) {
        v = W[(0 * 48 + c) * 32 + h] + W[(2 * 48 + c) * 32 + h];
    } else if (c < 32) {
        int cc = c - 16;
        v = W[(1 * 48 + cc) * 32 + h];
    } else {
        int cc = c - 32;
        v = W[(3 * 48 + cc) * 32 + h];
    }
    Wc[c * HID + h] = v;
}

// ---------------- per-node fused GRU-collapse + output ----------------
__global__ __launch_bounds__(256)
void node_kernel(const float* __restrict__ x, const float* __restrict__ To,
                 const float* __restrict__ Ti,
                 const float* __restrict__ Wzc, const float* __restrict__ Whc,
                 const float* __restrict__ bz, const float* __restrict__ bh,
                 const float* __restrict__ linW, const float* __restrict__ linb,
                 float* __restrict__ out) {
    __shared__ float sWz[CIN3 * HID];
    __shared__ float sWh[CIN3 * HID];
    __shared__ float sBz[HID], sBh[HID];
    __shared__ float sLW[HID * OUTD];
    __shared__ float sLb[OUTD];

    for (int i = threadIdx.x; i < CIN3 * HID; i += 256) { sWz[i] = Wzc[i]; sWh[i] = Whc[i]; }
    if (threadIdx.x < HID) { sBz[threadIdx.x] = bz[threadIdx.x]; sBh[threadIdx.x] = bh[threadIdx.x]; }
    for (int i = threadIdx.x; i < HID * OUTD; i += 256) sLW[i] = linW[i];
    if (threadIdx.x < OUTD) sLb[threadIdx.x] = linb[threadIdx.x];
    __syncthreads();

    int n = blockIdx.x * 256 + threadIdx.x;
    if (n >= N_NODES) return;

    float feat[CIN3];
#pragma unroll
    for (int q = 0; q < 4; ++q) {
        float4 v = ((const float4*)(x + (size_t)n * NF))[q];
        feat[q * 4 + 0] = v.x; feat[q * 4 + 1] = v.y; feat[q * 4 + 2] = v.z; feat[q * 4 + 3] = v.w;
    }
#pragma unroll
    for (int q = 0; q < 4; ++q) {
        float4 v = ((const float4*)(To + (size_t)n * NF))[q];
        feat[16 + q * 4 + 0] = v.x; feat[16 + q * 4 + 1] = v.y; feat[16 + q * 4 + 2] = v.z; feat[16 + q * 4 + 3] = v.w;
    }
#pragma unroll
    for (int q = 0; q < 4; ++q) {
        float4 v = ((const float4*)(Ti + (size_t)n * NF))[q];
        feat[32 + q * 4 + 0] = v.x; feat[32 + q * 4 + 1] = v.y; feat[32 + q * 4 + 2] = v.z; feat[32 + q * 4 + 3] = v.w;
    }

    float accz[HID], acch[HID];
#pragma unroll
    for (int h = 0; h < HID; ++h) { accz[h] = sBz[h]; acch[h] = sBh[h]; }

#pragma unroll
    for (int c = 0; c < CIN3; ++c) {
        float xv = feat[c];
#pragma unroll
        for (int q = 0; q < 8; ++q) {
            float4 wz = ((const float4*)sWz)[c * 8 + q];
            float4 wh = ((const float4*)sWh)[c * 8 + q];
            accz[q * 4 + 0] += xv * wz.x; accz[q * 4 + 1] += xv * wz.y;
            accz[q * 4 + 2] += xv * wz.z; accz[q * 4 + 3] += xv * wz.w;
            acch[q * 4 + 0] += xv * wh.x; acch[q * 4 + 1] += xv * wh.y;
            acch[q * 4 + 2] += xv * wh.z; acch[q * 4 + 3] += xv * wh.w;
        }
    }

    float hr[HID];
#pragma unroll
    for (int h = 0; h < HID; ++h) {
        float z  = 1.0f / (1.0f + expf(-accz[h]));
        float ht = tanhf(acch[h]);
        float hv = (1.0f - z) * ht;      // H = Z*H0 + (1-Z)*H_tilde, H0 = 0
        hr[h] = fmaxf(hv, 0.0f);         // relu
    }

    float o[OUTD];
#pragma unroll
    for (int j = 0; j < OUTD; ++j) o[j] = sLb[j];
#pragma unroll
    for (int h = 0; h < HID; ++h) {
        float r = hr[h];
#pragma unroll
        for (int j = 0; j < OUTD; ++j) o[j] += r * sLW[h * OUTD + j];
    }

    float4* op = (float4*)(out + (size_t)n * OUTD);
    op[0] = make_float4(o[0], o[1], o[2],  o[3]);
    op[1] = make_float4(o[4], o[5], o[6],  o[7]);
    op[2] = make_float4(o[8], o[9], o[10], o[11]);
}

extern "C" void kernel_launch(void* const* d_in, const int* in_sizes, int n_in,
                              void* d_out, int out_size, void* d_ws, size_t ws_size,
                              hipStream_t stream) {
    const float* x    = (const float*)d_in[0];
    const int*   ei   = (const int*)  d_in[1];
    const float* ew   = (const float*)d_in[2];
    const float* Wz   = (const float*)d_in[3];
    const float* bz   = (const float*)d_in[4];
    // d_in[5], d_in[6] (W_r, b_r) are dead: H0 == 0 makes R unused.
    const float* Wh   = (const float*)d_in[7];
    const float* bh   = (const float*)d_in[8];
    const float* linW = (const float*)d_in[9];
    const float* linb = (const float*)d_in[10];

    float* ws      = (float*)d_ws;
    float* deg_out = ws;                       // N   (becomes 1/deg_out)
    float* deg_in  = ws + N_NODES;             // N   (becomes 1/deg_in)
    float* To      = ws + 2 * N_NODES;         // 16N
    float* Ti      = ws + 18 * N_NODES;        // 16N
    float* Wzc     = ws + 34 * N_NODES;        // 48*32
    float* Whc     = Wzc + CIN3 * HID;         // 48*32

    const int zero_n = 34 * N_NODES;           // deg_out, deg_in, To, Ti
    zero_kernel<<<2048, 256, 0, stream>>>(ws, zero_n);

    degree_kernel<<<(N_EDGES + 255) / 256, 256, 0, stream>>>(ei, ew, deg_out, deg_in);
    rcp_kernel<<<(N_NODES + 255) / 256, 256, 0, stream>>>(deg_out, deg_in);
    scatter_kernel<<<(N_EDGES * NF + 255) / 256, 256, 0, stream>>>(ei, x, deg_out, deg_in, To, Ti);
    wprep_kernel<<<(2 * CIN3 * HID + 255) / 256, 256, 0, stream>>>(Wz, Wh, Wzc, Whc);
    node_kernel<<<(N_NODES + 255) / 256, 256, 0, stream>>>(x, To, Ti, Wzc, Whc, bz, bh,
                                                           linW, linb, (float*)d_out);
}

// Round 2
// 368.645 us; speedup vs baseline: 3.8496x; 3.8496x over previous
//
#include <hip/hip_runtime.h>
#include <math.h>

#define N_NODES 100000
#define N_EDGES 1600000
#define NF 16        // node features
#define HID 32
#define OUTD 12
#define CIN3 48      // x | T_o | T_i

// ---------------- zero workspace ----------------
__global__ void zero_kernel(float* __restrict__ p, int n) {
    int i = blockIdx.x * blockDim.x + threadIdx.x;
    int stride = gridDim.x * blockDim.x;
    for (; i < n; i += stride) p[i] = 0.0f;
}

// ---------------- weighted degrees ----------------
__global__ void degree_kernel(const int* __restrict__ ei, const float* __restrict__ ew,
                              float* __restrict__ deg_out, float* __restrict__ deg_in) {
    int e = blockIdx.x * blockDim.x + threadIdx.x;
    if (e >= N_EDGES) return;
    int src = ei[e];
    int dst = ei[N_EDGES + e];
    float w = ew[e];
    atomicAdd(&deg_out[src], w);
    atomicAdd(&deg_in[dst], w);
}

// ---------------- reciprocal in place ----------------
__global__ void rcp_kernel(float* __restrict__ deg_out, float* __restrict__ deg_in) {
    int n = blockIdx.x * blockDim.x + threadIdx.x;
    if (n >= N_NODES) return;
    deg_out[n] = 1.0f / deg_out[n];   // inf if degree 0 — never consumed (no such edge)
    deg_in[n]  = 1.0f / deg_in[n];
}

// ---------------- edge scatter: T_o / T_i ----------------
// thread t -> edge e = t>>4, feature f = t&15. 16 lanes per edge = coalesced 64B gathers.
__global__ __launch_bounds__(256)
void scatter_kernel(const int* __restrict__ ei, const float* __restrict__ x,
                    const float* __restrict__ inv_out, const float* __restrict__ inv_in,
                    float* __restrict__ To, float* __restrict__ Ti) {
    int t = blockIdx.x * blockDim.x + threadIdx.x;
    if (t >= N_EDGES * NF) return;
    int e = t >> 4;
    int f = t & 15;
    int src = ei[e];
    int dst = ei[N_EDGES + e];
    // forward diffusion: To[dst] += x[src] / deg_out[src]
    atomicAdd(&To[dst * NF + f], x[src * NF + f] * inv_out[src]);
    // reverse diffusion: Ti[src] += x[dst] / deg_in[dst]
    atomicAdd(&Ti[src * NF + f], x[dst * NF + f] * inv_in[dst]);
}

// ---------------- combine + TRANSPOSE weights: WT[h][c], h in [0,32), c in [0,48) ----------------
// c rows 0..15  : W[0,0,c,:] + W[1,0,c,:]   (K=0 term, both directions, only x-channels alive)
// c rows 16..31 : W[0,1,c-16,:]             (forward diffusion)
// c rows 32..47 : W[1,1,c-32,:]             (reverse diffusion)
// W layout [2,2,48,32]: (d,k,c,h) -> ((d*2+k)*48 + c)*32 + h
__global__ void wprep_kernel(const float* __restrict__ Wz, const float* __restrict__ Wh,
                             float* __restrict__ WzT, float* __restrict__ WhT) {
    int t = blockIdx.x * blockDim.x + threadIdx.x;
    if (t >= 2 * CIN3 * HID) return;
    const float* W = (t < CIN3 * HID) ? Wz : Wh;
    float* WT      = (t < CIN3 * HID) ? WzT : WhT;
    int i = (t < CIN3 * HID) ? t : (t - CIN3 * HID);
    int c = i / HID;
    int h = i - c * HID;
    float v;
    if (c < 16) {
        v = W[(0 * 48 + c) * 32 + h] + W[(2 * 48 + c) * 32 + h];
    } else if (c < 32) {
        int cc = c - 16;
        v = W[(1 * 48 + cc) * 32 + h];
    } else {
        int cc = c - 32;
        v = W[(3 * 48 + cc) * 32 + h];
    }
    WT[h * CIN3 + c] = v;   // transposed: [HID][CIN3]
}

// ---------------- per-node fused GRU-collapse + output ----------------
// Register budget: feat[48] + o[12] + scalars -> no accumulator arrays, no spill.
__global__ __launch_bounds__(256)
void node_kernel(const float* __restrict__ x, const float* __restrict__ To,
                 const float* __restrict__ Ti,
                 const float* __restrict__ WzT, const float* __restrict__ WhT,
                 const float* __restrict__ bz, const float* __restrict__ bh,
                 const float* __restrict__ linW, const float* __restrict__ linb,
                 float* __restrict__ out) {
    __shared__ __align__(16) float sWz[HID * CIN3];   // [h][c]
    __shared__ __align__(16) float sWh[HID * CIN3];   // [h][c]
    __shared__ __align__(16) float sBz[HID], sBh[HID];
    __shared__ __align__(16) float sLW[HID * OUTD];   // [h][j]
    __shared__ __align__(16) float sLb[OUTD];

    for (int i = threadIdx.x; i < HID * CIN3; i += 256) { sWz[i] = WzT[i]; sWh[i] = WhT[i]; }
    if (threadIdx.x < HID) { sBz[threadIdx.x] = bz[threadIdx.x]; sBh[threadIdx.x] = bh[threadIdx.x]; }
    for (int i = threadIdx.x; i < HID * OUTD; i += 256) sLW[i] = linW[i];
    if (threadIdx.x < OUTD) sLb[threadIdx.x] = linb[threadIdx.x];
    __syncthreads();

    int n = blockIdx.x * 256 + threadIdx.x;
    if (n >= N_NODES) return;

    float feat[CIN3];
#pragma unroll
    for (int q = 0; q < 4; ++q) {
        float4 v = ((const float4*)(x + (size_t)n * NF))[q];
        feat[q * 4 + 0] = v.x; feat[q * 4 + 1] = v.y; feat[q * 4 + 2] = v.z; feat[q * 4 + 3] = v.w;
    }
#pragma unroll
    for (int q = 0; q < 4; ++q) {
        float4 v = ((const float4*)(To + (size_t)n * NF))[q];
        feat[16 + q * 4 + 0] = v.x; feat[16 + q * 4 + 1] = v.y; feat[16 + q * 4 + 2] = v.z; feat[16 + q * 4 + 3] = v.w;
    }
#pragma unroll
    for (int q = 0; q < 4; ++q) {
        float4 v = ((const float4*)(Ti + (size_t)n * NF))[q];
        feat[32 + q * 4 + 0] = v.x; feat[32 + q * 4 + 1] = v.y; feat[32 + q * 4 + 2] = v.z; feat[32 + q * 4 + 3] = v.w;
    }

    float o[OUTD];
#pragma unroll
    for (int j = 0; j < OUTD; ++j) o[j] = sLb[j];

#pragma unroll 2
    for (int h = 0; h < HID; ++h) {
        float az = sBz[h];
        float ah = sBh[h];
        const float4* wz4 = (const float4*)(sWz + h * CIN3);
        const float4* wh4 = (const float4*)(sWh + h * CIN3);
#pragma unroll
        for (int q = 0; q < CIN3 / 4; ++q) {
            float4 wz = wz4[q];
            float4 wh = wh4[q];
            float f0 = feat[q * 4 + 0], f1 = feat[q * 4 + 1];
            float f2 = feat[q * 4 + 2], f3 = feat[q * 4 + 3];
            az += f0 * wz.x + f1 * wz.y + f2 * wz.z + f3 * wz.w;
            ah += f0 * wh.x + f1 * wh.y + f2 * wh.z + f3 * wh.w;
        }
        float z  = 1.0f / (1.0f + expf(-az));
        float ht = tanhf(ah);
        float r  = fmaxf((1.0f - z) * ht, 0.0f);   // H = (1-Z)*H_tilde (H0=0), then relu
#pragma unroll
        for (int j = 0; j < OUTD; ++j) o[j] += r * sLW[h * OUTD + j];
    }

    float4* op = (float4*)(out + (size_t)n * OUTD);
    op[0] = make_float4(o[0], o[1], o[2],  o[3]);
    op[1] = make_float4(o[4], o[5], o[6],  o[7]);
    op[2] = make_float4(o[8], o[9], o[10], o[11]);
}

extern "C" void kernel_launch(void* const* d_in, const int* in_sizes, int n_in,
                              void* d_out, int out_size, void* d_ws, size_t ws_size,
                              hipStream_t stream) {
    const float* x    = (const float*)d_in[0];
    const int*   ei   = (const int*)  d_in[1];
    const float* ew   = (const float*)d_in[2];
    const float* Wz   = (const float*)d_in[3];
    const float* bz   = (const float*)d_in[4];
    // d_in[5], d_in[6] (W_r, b_r) are dead: H0 == 0 makes R unused.
    const float* Wh   = (const float*)d_in[7];
    const float* bh   = (const float*)d_in[8];
    const float* linW = (const float*)d_in[9];
    const float* linb = (const float*)d_in[10];

    float* ws      = (float*)d_ws;
    float* deg_out = ws;                       // N   (becomes 1/deg_out)
    float* deg_in  = ws + N_NODES;             // N   (becomes 1/deg_in)
    float* To      = ws + 2 * N_NODES;         // 16N
    float* Ti      = ws + 18 * N_NODES;        // 16N
    float* WzT     = ws + 34 * N_NODES;        // 32*48 (transposed combined)
    float* WhT     = WzT + CIN3 * HID;         // 32*48

    const int zero_n = 34 * N_NODES;           // deg_out, deg_in, To, Ti
    zero_kernel<<<2048, 256, 0, stream>>>(ws, zero_n);

    degree_kernel<<<(N_EDGES + 255) / 256, 256, 0, stream>>>(ei, ew, deg_out, deg_in);
    rcp_kernel<<<(N_NODES + 255) / 256, 256, 0, stream>>>(deg_out, deg_in);
    scatter_kernel<<<(N_EDGES * NF + 255) / 256, 256, 0, stream>>>(ei, x, deg_out, deg_in, To, Ti);
    wprep_kernel<<<(2 * CIN3 * HID + 255) / 256, 256, 0, stream>>>(Wz, Wh, WzT, WhT);
    node_kernel<<<(N_NODES + 255) / 256, 256, 0, stream>>>(x, To, Ti, WzT, WhT, bz, bh,
                                                           linW, linb, (float*)d_out);
}